// Round 6
// baseline (243.415 us; speedup 1.0000x reference)
//
#include <hip/hip_runtime.h>

#define DDIM 256
#define NTOK 4096   // B*S = 64*64
#define NEGN 8192
// small 64x64 kernel (fr alignment)
#define TM 64
#define TN 64
#define LDT 40      // padded halfs per LDS row for the small kernel

typedef __attribute__((ext_vector_type(8))) short bf16x8;
typedef __attribute__((ext_vector_type(4))) float f32x4;

__device__ inline unsigned short f2bf(float f) {
    unsigned int u = __float_as_uint(f);
    unsigned int r = u + 0x7FFFu + ((u >> 16) & 1u);
    return (unsigned short)(r >> 16);
}

// global->LDS direct DMA, 16B/lane; LDS dest = wave-uniform base + lane*16.
__device__ inline void gl_lds16(const unsigned short* g, unsigned short* l) {
    __builtin_amdgcn_global_load_lds(
        reinterpret_cast<__attribute__((address_space(1))) unsigned int*>(
            reinterpret_cast<uintptr_t>(g)),
        reinterpret_cast<__attribute__((address_space(3))) unsigned int*>(
            reinterpret_cast<uintptr_t>(l)),
        16, 0, 0);
}

// stage one 64-row x 32-half chunk (4 sub-tiles of 16 rows) for this wave.
// gbase already folds (rowbase + col)*DDIM + kk + quad*8.
__device__ inline void dma_chunk(const unsigned short* gbase, unsigned short* ldsbase) {
    #pragma unroll
    for (int s = 0; s < 4; s++)
        gl_lds16(gbase + (size_t)s * 16 * DDIM, ldsbase + s * 512);
}

// DPP 16-lane sum reduction — VALU only.
template<int CTRL>
__device__ inline float dpp_add(float x) {
    int v = __builtin_amdgcn_update_dpp(0, __float_as_int(x), CTRL, 0xF, 0xF, false);
    return x + __int_as_float(v);
}
__device__ inline float red16(float x) {
    x = dpp_add<0xB1>(x);    // quad_perm [1,0,3,2]
    x = dpp_add<0x4E>(x);    // quad_perm [2,3,0,1]
    x = dpp_add<0x141>(x);   // row_half_mirror
    x = dpp_add<0x140>(x);   // row_mirror
    return x;
}

// ---------------------------------------------------------------------------
// Kernel 1: gather + fp32->bf16 convert + fused en_score + denom zero-init.
// Row space: z | E_en | E_fr | en_score-rows.
// ---------------------------------------------------------------------------
__global__ void gather_kernel(
    const float* __restrict__ zs,
    const float* __restrict__ W_en, const float* __restrict__ W_fr,
    const int* __restrict__ pos_en, const int* __restrict__ neg_en,
    const int* __restrict__ pos_fr, const int* __restrict__ neg_fr,
    const int* __restrict__ x_en,
    const float* __restrict__ kappa_en, const float* __restrict__ kappa_fr,
    unsigned short* __restrict__ z_bf,
    unsigned short* __restrict__ E_en, unsigned short* __restrict__ E_fr,
    float* __restrict__ w_en, float* __restrict__ w_fr,
    float* __restrict__ en_score,
    float* __restrict__ denom_en, float* __restrict__ denom_fr,
    int Pe, int Pf, int Lpe, int Lpf)
{
    int row  = blockIdx.x * 4 + (threadIdx.x >> 6);
    int lane = threadIdx.x & 63;
    const float* src = nullptr;
    unsigned short* dst = nullptr;
    bool zero = false;

    if (row < NTOK) {
        src = zs + (size_t)row * DDIM;
        dst = z_bf + (size_t)row * DDIM;
        if (lane == 0) { denom_en[row] = 0.0f; denom_fr[row] = 0.0f; }
    } else if (row < NTOK + Lpe) {
        int j = row - NTOK;
        int Le = Pe + NEGN;
        int idx = 0;
        if (j < Pe)      idx = pos_en[j];
        else if (j < Le) idx = neg_en[j - Pe];
        else             zero = true;
        src = W_en + (size_t)idx * DDIM;
        dst = E_en + (size_t)j * DDIM;
        if (lane == 0) w_en[j] = (j < Pe) ? 1.0f : (j < Le ? kappa_en[0] : 0.0f);
    } else if (row < NTOK + Lpe + Lpf) {
        int j = row - NTOK - Lpe;
        int Lf = Pf + NEGN;
        int idx = 0;
        if (j < Pf)      idx = pos_fr[j];
        else if (j < Lf) idx = neg_fr[j - Pf];
        else             zero = true;
        src = W_fr + (size_t)idx * DDIM;
        dst = E_fr + (size_t)j * DDIM;
        if (lane == 0) w_fr[j] = (j < Pf) ? 1.0f : (j < Lf ? kappa_fr[0] : 0.0f);
    } else if (row < NTOK + Lpe + Lpf + NTOK) {
        // fused en_score: zs[j] . W_en[x_en[j]] in fp32, wave reduce
        int j = row - NTOK - Lpe - Lpf;
        int idx = x_en[j];
        float4 z = *(const float4*)(zs   + (size_t)j   * DDIM + lane * 4);
        float4 w = *(const float4*)(W_en + (size_t)idx * DDIM + lane * 4);
        float s = z.x * w.x + z.y * w.y + z.z * w.z + z.w * w.w;
        #pragma unroll
        for (int m = 32; m; m >>= 1) s += __shfl_xor(s, m);
        if (lane == 0) en_score[j] = s;
        return;
    } else {
        return;
    }

    int d = lane * 4;
    float4 v;
    if (zero) { v.x = v.y = v.z = v.w = 0.0f; }
    else      { v = *(const float4*)(src + d); }
    ushort4 o;
    o.x = f2bf(v.x); o.y = f2bf(v.y); o.z = f2bf(v.z); o.w = f2bf(v.w);
    *(ushort4*)(dst + d) = o;
}

// ---------------------------------------------------------------------------
// Kernel 2: fused denominators — BARRIER-FREE n-streaming GEMM (AITER-style).
// Block = 4 waves (2m x 2n), block tile 128m x 128n. A (z rows) in registers
// for the whole stream. Each wave stages its OWN 64-row B chunk into a
// per-wave LDS double buffer via global_load_lds (chunk-major, conflict-free)
// — no cross-wave sharing, so NO __syncthreads anywhere. Sync is
// s_waitcnt vmcnt(4): wait for the previous chunk's 4 DMAs while the just-
// issued next-chunk 4 remain in flight (in-order vmcnt retirement makes any
// extra outstanding wts/atomic ops strictly-safe). Pipeline is continuous
// across n-tiles; per-tile epilogue overlaps the next tile's first DMA.
// Frag layouts (HW-verified rounds 1-5, absmax 0.0):
//   A/B: lane holds row (lane&15), 8 k-halfs at (lane>>4)*8
//   C/D: n-col = lane&15, m-row = (lane>>4)*4 + reg
// ---------------------------------------------------------------------------
__global__ __launch_bounds__(256, 2) void expsum_stream(
    const unsigned short* __restrict__ A,   // z_bf [4096 x 256]
    const unsigned short* __restrict__ E,   // [Ltot x 256]
    const float* __restrict__ wts,          // [Ltot]
    float* __restrict__ out_en, float* __restrict__ out_fr,
    int Lpe, int NT)                         // NT = Ltot/128 n-tiles
{
    __shared__ __align__(16) unsigned short Bs[4][2][2048];  // [wave][buf]

    // XCD clustering: xcd = fid%8 owns y-segments {2*xcd, 2*xcd+1}
    int fid = blockIdx.y * 32 + blockIdx.x;
    int xcd = fid & 7;
    int r   = fid >> 3;                // 0..63
    int yb  = xcd * 2 + (r & 1);       // 0..15
    int xb  = r >> 1;                  // 0..31

    int t    = threadIdx.x;
    int lane = t & 63;
    int wave = t >> 6;
    int col  = lane & 15;
    int quad = lane >> 4;
    int wm   = wave & 1;
    int wn   = wave >> 1;

    // ---- A fragments in registers (one-time load)
    bf16x8 afr[4][8];
    {
        const unsigned short* Ap =
            A + ((size_t)(xb * 128 + wm * 64 + col)) * DDIM + quad * 8;
        #pragma unroll
        for (int i = 0; i < 4; i++)
            #pragma unroll
            for (int c = 0; c < 8; c++)
                afr[i][c] = *(const bf16x8*)(Ap + (size_t)i * 16 * DDIM + c * 32);
    }

    float sums[4][4];
    #pragma unroll
    for (int i = 0; i < 4; i++)
        #pragma unroll
        for (int rr = 0; rr < 4; rr++) sums[i][rr] = 0.0f;
    float* curout = out_en;
    int outrow = xb * 128 + wm * 64;

    unsigned short* lds0 = &Bs[wave][0][0];
    unsigned short* lds1 = &Bs[wave][1][0];

    // prefetch chunk 0 of first tile into buffer 0
    dma_chunk(E + (size_t)(yb * 128 + wn * 64 + col) * DDIM + quad * 8, lds0);

    int p = 0;
    for (int tl = yb; tl < NT; tl += 16) {
        int nb = tl * 128;
        const unsigned short* gtile =
            E + (size_t)(nb + wn * 64 + col) * DDIM + quad * 8;

        float wj[4];
        #pragma unroll
        for (int j = 0; j < 4; j++)
            wj[j] = wts[nb + wn * 64 + 16 * j + col];

        float* o = (nb >= Lpe) ? out_fr : out_en;
        if (o != curout) {
            // flush en sums at the en->fr boundary (stream is monotone)
            if (col == 0) {
                #pragma unroll
                for (int i = 0; i < 4; i++)
                    #pragma unroll
                    for (int rr = 0; rr < 4; rr++)
                        atomicAdd(curout + outrow + 16 * i + quad * 4 + rr, sums[i][rr]);
            }
            #pragma unroll
            for (int i = 0; i < 4; i++)
                #pragma unroll
                for (int rr = 0; rr < 4; rr++) sums[i][rr] = 0.0f;
            curout = o;
        }

        f32x4 acc[4][4];
        #pragma unroll
        for (int i = 0; i < 4; i++)
            #pragma unroll
            for (int j = 0; j < 4; j++)
                acc[i][j] = (f32x4){0.f, 0.f, 0.f, 0.f};

        #pragma unroll
        for (int k8 = 0; k8 < 8; k8++) {
            unsigned short* cbuf = p ? lds1 : lds0;
            unsigned short* nbuf = p ? lds0 : lds1;
            if (k8 < 7) {
                dma_chunk(gtile + (k8 + 1) * 32, nbuf);
                asm volatile("s_waitcnt vmcnt(4)" ::: "memory");
            } else if (tl + 16 < NT) {
                dma_chunk(E + (size_t)((tl + 16) * 128 + wn * 64 + col) * DDIM + quad * 8,
                          nbuf);
                asm volatile("s_waitcnt vmcnt(4)" ::: "memory");
            } else {
                asm volatile("s_waitcnt vmcnt(0)" ::: "memory");
            }
            bf16x8 bfv[4];
            #pragma unroll
            for (int j = 0; j < 4; j++)
                bfv[j] = *(const bf16x8*)(cbuf + j * 512 + quad * 128 + col * 8);
            #pragma unroll
            for (int j = 0; j < 4; j++)
                #pragma unroll
                for (int i = 0; i < 4; i++)
                    acc[i][j] = __builtin_amdgcn_mfma_f32_16x16x32_bf16(
                        afr[i][k8], bfv[j], acc[i][j], 0, 0, 0);
            p ^= 1;
        }

        // per-tile epilogue: weighted exp, DPP-reduce over 64 n, accumulate
        #pragma unroll
        for (int i = 0; i < 4; i++)
            #pragma unroll
            for (int rr = 0; rr < 4; rr++) {
                float s = wj[0] * __expf(acc[i][0][rr]) + wj[1] * __expf(acc[i][1][rr])
                        + wj[2] * __expf(acc[i][2][rr]) + wj[3] * __expf(acc[i][3][rr]);
                sums[i][rr] += red16(s);
            }
    }

    // final flush
    if (col == 0) {
        #pragma unroll
        for (int i = 0; i < 4; i++)
            #pragma unroll
            for (int rr = 0; rr < 4; rr++)
                atomicAdd(curout + outrow + 16 * i + quad * 4 + rr, sums[i][rr]);
    }
}

// ---------------------------------------------------------------------------
// Kernel 3: fr alignment (per-batch 64x64 exp-sum, weight 1/denom_fr) with
// inline W_fr[x_fr] gather+convert for A and the final loss fused in.
// ---------------------------------------------------------------------------
__global__ __launch_bounds__(256) void expsum_gemm64_loss(
    const float* __restrict__ W_fr,         // [V_FR x 256] fp32
    const int* __restrict__ x_fr,           // [B*64]
    const unsigned short* __restrict__ Bm,  // z_bf  [B][64 x 256]
    const float* __restrict__ denom_fr,     // [B*64]
    const float* __restrict__ denom_en,     // [B*64]
    const float* __restrict__ en_score,     // [B*64]
    const float* __restrict__ en_mask,
    const float* __restrict__ fr_mask,
    float* __restrict__ outloss)            // [128]: en | fr
{
    __shared__ __align__(16) unsigned short lda[TM * LDT];
    __shared__ __align__(16) unsigned short ldb[TN * LDT];
    __shared__ float tbuf[64];

    int batch = blockIdx.x;
    const unsigned short* Bb = Bm + (size_t)batch * TN * DDIM;

    int t      = threadIdx.x;
    int srow   = t >> 2;
    int schunk = t & 3;
    int lane   = t & 63;
    int wave   = t >> 6;
    int col    = lane & 15;
    int quad   = lane >> 4;

    int aidx = x_fr[batch * 64 + srow];
    const float* Arow = W_fr + (size_t)aidx * DDIM;

    f32x4 acc0 = {0.f,0.f,0.f,0.f};
    f32x4 acc1 = {0.f,0.f,0.f,0.f};
    f32x4 acc2 = {0.f,0.f,0.f,0.f};
    f32x4 acc3 = {0.f,0.f,0.f,0.f};

    for (int kk = 0; kk < DDIM; kk += 32) {
        float4 f0 = *(const float4*)(Arow + kk + schunk * 8);
        float4 f1 = *(const float4*)(Arow + kk + schunk * 8 + 4);
        uint4 bv = *(const uint4*)(Bb + (size_t)srow * DDIM + kk + schunk * 8);
        ushort4 ua; ua.x = f2bf(f0.x); ua.y = f2bf(f0.y); ua.z = f2bf(f0.z); ua.w = f2bf(f0.w);
        ushort4 ub; ub.x = f2bf(f1.x); ub.y = f2bf(f1.y); ub.z = f2bf(f1.z); ub.w = f2bf(f1.w);
        __syncthreads();
        *(ushort4*)(lda + srow * LDT + schunk * 8)     = ua;
        *(ushort4*)(lda + srow * LDT + schunk * 8 + 4) = ub;
        *(uint4*)(ldb + srow * LDT + schunk * 8) = bv;
        __syncthreads();

        bf16x8 af = *(const bf16x8*)(lda + (wave * 16 + col) * LDT + quad * 8);
        bf16x8 b0 = *(const bf16x8*)(ldb + ( 0 + col) * LDT + quad * 8);
        bf16x8 b1 = *(const bf16x8*)(ldb + (16 + col) * LDT + quad * 8);
        bf16x8 b2 = *(const bf16x8*)(ldb + (32 + col) * LDT + quad * 8);
        bf16x8 b3 = *(const bf16x8*)(ldb + (48 + col) * LDT + quad * 8);
        acc0 = __builtin_amdgcn_mfma_f32_16x16x32_bf16(af, b0, acc0, 0, 0, 0);
        acc1 = __builtin_amdgcn_mfma_f32_16x16x32_bf16(af, b1, acc1, 0, 0, 0);
        acc2 = __builtin_amdgcn_mfma_f32_16x16x32_bf16(af, b2, acc2, 0, 0, 0);
        acc3 = __builtin_amdgcn_mfma_f32_16x16x32_bf16(af, b3, acc3, 0, 0, 0);
    }

    const float* db = denom_fr + batch * 64;
    float w0 = 1.0f / db[ 0 + col];
    float w1 = 1.0f / db[16 + col];
    float w2 = 1.0f / db[32 + col];
    float w3 = 1.0f / db[48 + col];

    float tot0 = w0 * __expf(acc0.x) + w1 * __expf(acc1.x) + w2 * __expf(acc2.x) + w3 * __expf(acc3.x);
    float tot1 = w0 * __expf(acc0.y) + w1 * __expf(acc1.y) + w2 * __expf(acc2.y) + w3 * __expf(acc3.y);
    float tot2 = w0 * __expf(acc0.z) + w1 * __expf(acc1.z) + w2 * __expf(acc2.z) + w3 * __expf(acc3.z);
    float tot3 = w0 * __expf(acc0.w) + w1 * __expf(acc1.w) + w2 * __expf(acc2.w) + w3 * __expf(acc3.w);

    #pragma unroll
    for (int m = 1; m < 16; m <<= 1) {
        tot0 += __shfl_xor(tot0, m);
        tot1 += __shfl_xor(tot1, m);
        tot2 += __shfl_xor(tot2, m);
        tot3 += __shfl_xor(tot3, m);
    }
    if (col == 0) {
        int base = wave * 16 + quad * 4;
        tbuf[base + 0] = tot0; tbuf[base + 1] = tot1;
        tbuf[base + 2] = tot2; tbuf[base + 3] = tot3;
    }
    __syncthreads();

    if (t < 64) {
        int i = batch * 64 + t;
        float a = (en_score[i] - __logf(denom_en[i])) * en_mask[i];
        float c = __logf(tbuf[t]) * fr_mask[i];
        #pragma unroll
        for (int m = 32; m; m >>= 1) { a += __shfl_xor(a, m); c += __shfl_xor(c, m); }
        if (t == 0) { outloss[batch] = a; outloss[64 + batch] = c; }
    }
}

extern "C" void kernel_launch(void* const* d_in, const int* in_sizes, int n_in,
                              void* d_out, int out_size, void* d_ws, size_t ws_size,
                              hipStream_t stream)
{
    const float* zs       = (const float*)d_in[0];
    const int*   x_en     = (const int*)d_in[1];
    const int*   x_fr     = (const int*)d_in[2];
    const float* en_mask  = (const float*)d_in[3];
    const float* fr_mask  = (const float*)d_in[4];
    const float* W_en     = (const float*)d_in[5];
    const float* W_fr     = (const float*)d_in[6];
    const int*   pos_en   = (const int*)d_in[7];
    const int*   neg_en   = (const int*)d_in[8];
    const int*   pos_fr   = (const int*)d_in[9];
    const int*   neg_fr   = (const int*)d_in[10];
    const float* kappa_en = (const float*)d_in[11];
    const float* kappa_fr = (const float*)d_in[12];

    int Pe  = in_sizes[7];
    int Pf  = in_sizes[9];
    int Lpe = (Pe + NEGN + 127) & ~127;   // 128-aligned n-tiles
    int Lpf = (Pf + NEGN + 127) & ~127;
    int Ltot = Lpe + Lpf;
    int NT   = Ltot / 128;

    char* w = (char*)d_ws;
    float* denom_en = (float*)w; w += NTOK * 4;
    float* denom_fr = (float*)w; w += NTOK * 4;
    float* en_score = (float*)w; w += NTOK * 4;
    float* w_all    = (float*)w; w += (size_t)Ltot * 4;
    unsigned short* z_bf  = (unsigned short*)w; w += (size_t)NTOK * DDIM * 2;
    unsigned short* E_all = (unsigned short*)w; w += (size_t)Ltot * DDIM * 2;

    int totrows = NTOK + Lpe + Lpf + NTOK;
    gather_kernel<<<(totrows + 3) / 4, 256, 0, stream>>>(
        zs, W_en, W_fr, pos_en, neg_en, pos_fr, neg_fr, x_en,
        kappa_en, kappa_fr, z_bf, E_all, E_all + (size_t)Lpe * DDIM,
        w_all, w_all + Lpe, en_score, denom_en, denom_fr, Pe, Pf, Lpe, Lpf);

    // fused denominators: barrier-free n-streaming register-A GEMM
    expsum_stream<<<dim3(32, 16), 256, 0, stream>>>(
        z_bf, E_all, w_all, denom_en, denom_fr, Lpe, NT);

    // fr alignment + inline W_fr gather + fused loss
    expsum_gemm64_loss<<<64, 256, 0, stream>>>(
        W_fr, x_fr, z_bf, denom_fr, denom_en, en_score, en_mask, fr_mask,
        (float*)d_out);
}

// Round 7
// 208.796 us; speedup vs baseline: 1.1658x; 1.1658x over previous
//
#include <hip/hip_runtime.h>

#define DDIM 256
#define NTOK 4096   // B*S = 64*64
#define NEGN 8192
// small 64x64 kernel (fr alignment)
#define TM 64
#define TN 64
#define LDT 40      // padded halfs per LDS row for the small kernel

typedef __attribute__((ext_vector_type(8))) short bf16x8;
typedef __attribute__((ext_vector_type(4))) float f32x4;

__device__ inline unsigned short f2bf(float f) {
    unsigned int u = __float_as_uint(f);
    unsigned int r = u + 0x7FFFu + ((u >> 16) & 1u);
    return (unsigned short)(r >> 16);
}

// global->LDS direct DMA, 16B/lane; LDS dest = wave-uniform base + lane*16.
__device__ inline void gl_lds16(const unsigned short* g, unsigned short* l) {
    __builtin_amdgcn_global_load_lds(
        reinterpret_cast<__attribute__((address_space(1))) unsigned int*>(
            reinterpret_cast<uintptr_t>(g)),
        reinterpret_cast<__attribute__((address_space(3))) unsigned int*>(
            reinterpret_cast<uintptr_t>(l)),
        16, 0, 0);
}

__device__ inline void wait_vmcnt4() { asm volatile("s_waitcnt vmcnt(4)" ::: "memory"); }
__device__ inline void wait_vmcnt2() { asm volatile("s_waitcnt vmcnt(2)" ::: "memory"); }
__device__ inline void wait_vmcnt0() { asm volatile("s_waitcnt vmcnt(0)" ::: "memory"); }
__device__ inline void raw_barrier() { asm volatile("s_barrier" ::: "memory"); }

// DPP 16-lane sum reduction — VALU only.
template<int CTRL>
__device__ inline float dpp_add(float x) {
    int v = __builtin_amdgcn_update_dpp(0, __float_as_int(x), CTRL, 0xF, 0xF, false);
    return x + __int_as_float(v);
}
__device__ inline float red16(float x) {
    x = dpp_add<0xB1>(x);    // quad_perm [1,0,3,2]
    x = dpp_add<0x4E>(x);    // quad_perm [2,3,0,1]
    x = dpp_add<0x141>(x);   // row_half_mirror
    x = dpp_add<0x140>(x);   // row_mirror
    return x;
}

// ---------------------------------------------------------------------------
// Kernel 1: gather + fp32->bf16 convert + fused en_score + denom zero-init.
// ---------------------------------------------------------------------------
__global__ void gather_kernel(
    const float* __restrict__ zs,
    const float* __restrict__ W_en, const float* __restrict__ W_fr,
    const int* __restrict__ pos_en, const int* __restrict__ neg_en,
    const int* __restrict__ pos_fr, const int* __restrict__ neg_fr,
    const int* __restrict__ x_en,
    const float* __restrict__ kappa_en, const float* __restrict__ kappa_fr,
    unsigned short* __restrict__ z_bf,
    unsigned short* __restrict__ E_en, unsigned short* __restrict__ E_fr,
    float* __restrict__ w_en, float* __restrict__ w_fr,
    float* __restrict__ en_score,
    float* __restrict__ denom_en, float* __restrict__ denom_fr,
    int Pe, int Pf, int Lpe, int Lpf)
{
    int row  = blockIdx.x * 4 + (threadIdx.x >> 6);
    int lane = threadIdx.x & 63;
    const float* src = nullptr;
    unsigned short* dst = nullptr;
    bool zero = false;

    if (row < NTOK) {
        src = zs + (size_t)row * DDIM;
        dst = z_bf + (size_t)row * DDIM;
        if (lane == 0) { denom_en[row] = 0.0f; denom_fr[row] = 0.0f; }
    } else if (row < NTOK + Lpe) {
        int j = row - NTOK;
        int Le = Pe + NEGN;
        int idx = 0;
        if (j < Pe)      idx = pos_en[j];
        else if (j < Le) idx = neg_en[j - Pe];
        else             zero = true;
        src = W_en + (size_t)idx * DDIM;
        dst = E_en + (size_t)j * DDIM;
        if (lane == 0) w_en[j] = (j < Pe) ? 1.0f : (j < Le ? kappa_en[0] : 0.0f);
    } else if (row < NTOK + Lpe + Lpf) {
        int j = row - NTOK - Lpe;
        int Lf = Pf + NEGN;
        int idx = 0;
        if (j < Pf)      idx = pos_fr[j];
        else if (j < Lf) idx = neg_fr[j - Pf];
        else             zero = true;
        src = W_fr + (size_t)idx * DDIM;
        dst = E_fr + (size_t)j * DDIM;
        if (lane == 0) w_fr[j] = (j < Pf) ? 1.0f : (j < Lf ? kappa_fr[0] : 0.0f);
    } else if (row < NTOK + Lpe + Lpf + NTOK) {
        // fused en_score: zs[j] . W_en[x_en[j]] in fp32, wave reduce
        int j = row - NTOK - Lpe - Lpf;
        int idx = x_en[j];
        float4 z = *(const float4*)(zs   + (size_t)j   * DDIM + lane * 4);
        float4 w = *(const float4*)(W_en + (size_t)idx * DDIM + lane * 4);
        float s = z.x * w.x + z.y * w.y + z.z * w.z + z.w * w.w;
        #pragma unroll
        for (int m = 32; m; m >>= 1) s += __shfl_xor(s, m);
        if (lane == 0) en_score[j] = s;
        return;
    } else {
        return;
    }

    int d = lane * 4;
    float4 v;
    if (zero) { v.x = v.y = v.z = v.w = 0.0f; }
    else      { v = *(const float4*)(src + d); }
    ushort4 o;
    o.x = f2bf(v.x); o.y = f2bf(v.y); o.z = f2bf(v.z); o.w = f2bf(v.w);
    *(ushort4*)(dst + d) = o;
}

// ---------------------------------------------------------------------------
// Kernel 2: fused denominators — shared staging + raw barrier + fine vmcnt.
// Block = 4 waves (2m x 2n), tile 128m x 128n streamed over n. A in registers
// (whole K). B chunks (128 rows x 32 halfs) staged cooperatively (8 DMAs per
// chunk per block, chunk-major conflict-free layout) into a 4-slot LDS ring.
// Pipeline per chunk c: stage(c+2) -> s_waitcnt vmcnt(4) [waits chunk c only;
// c+1,c+2 remain in flight] -> raw s_barrier (no compiler vmcnt(0) drain!)
// -> ds_read slot[c&3] -> 16 MFMAs. Ring-4 reuse overwrites c-2's slot whose
// reads completed before the previous barrier (MFMA consumption forces it).
// Frag layouts (HW-verified rounds 1-6, absmax 0.0):
//   A/B: lane holds row (lane&15), 8 k-halfs at (lane>>4)*8
//   C/D: n-col = lane&15, m-row = (lane>>4)*4 + reg
// ---------------------------------------------------------------------------
__global__ __launch_bounds__(256, 2) void expsum_stream(
    const unsigned short* __restrict__ A,   // z_bf [4096 x 256]
    const unsigned short* __restrict__ E,   // [Ltot x 256]
    const float* __restrict__ wts,          // [Ltot]
    float* __restrict__ out_en, float* __restrict__ out_fr,
    int Lpe, int NT)                         // NT = Ltot/128 n-tiles
{
    __shared__ __align__(16) unsigned short Bs[4][4096];  // 4-slot ring, 8KB each

    // XCD clustering: xcd = fid%8 owns y-segments {2*xcd, 2*xcd+1}
    int fid = blockIdx.y * 32 + blockIdx.x;
    int xcd = fid & 7;
    int r   = fid >> 3;                // 0..63
    int yb  = xcd * 2 + (r & 1);       // 0..15
    int xb  = r >> 1;                  // 0..31

    int t    = threadIdx.x;
    int lane = t & 63;
    int wave = t >> 6;
    int col  = lane & 15;
    int quad = lane >> 4;
    int wm   = wave & 1;
    int wn   = wave >> 1;

    // ---- A fragments in registers (one-time load)
    bf16x8 afr[4][8];
    {
        const unsigned short* Ap =
            A + ((size_t)(xb * 128 + wm * 64 + col)) * DDIM + quad * 8;
        #pragma unroll
        for (int i = 0; i < 4; i++)
            #pragma unroll
            for (int c = 0; c < 8; c++)
                afr[i][c] = *(const bf16x8*)(Ap + (size_t)i * 16 * DDIM + c * 32);
    }

    float sums[4][4];
    #pragma unroll
    for (int i = 0; i < 4; i++)
        #pragma unroll
        for (int rr = 0; rr < 4; rr++) sums[i][rr] = 0.0f;
    float* curout = out_en;
    int outrow = xb * 128 + wm * 64;

    int ntiles = (NT - yb + 15) >> 4;

    // prologue: stage chunk 0 -> slot 0, chunk 1 -> slot 1
    {
        const unsigned short* g0 =
            E + (size_t)(yb * 128 + 32 * wave + col) * DDIM + quad * 8;
        gl_lds16(g0,                 &Bs[0][wave * 1024]);
        gl_lds16(g0 + 16 * DDIM,     &Bs[0][wave * 1024 + 512]);
        gl_lds16(g0 + 32,            &Bs[1][wave * 1024]);
        gl_lds16(g0 + 16 * DDIM + 32,&Bs[1][wave * 1024 + 512]);
    }

    for (int s = 0; s < ntiles; s++) {
        int tl = yb + (s << 4);
        int nb = tl * 128;
        bool last = (s == ntiles - 1);

        float wj[4];
        #pragma unroll
        for (int j = 0; j < 4; j++)
            wj[j] = wts[nb + wn * 64 + 16 * j + col];

        float* o = (nb >= Lpe) ? out_fr : out_en;
        if (o != curout) {
            // flush en sums at the en->fr boundary (stream is monotone)
            if (col == 0) {
                #pragma unroll
                for (int i = 0; i < 4; i++)
                    #pragma unroll
                    for (int rr = 0; rr < 4; rr++)
                        atomicAdd(curout + outrow + 16 * i + quad * 4 + rr, sums[i][rr]);
            }
            #pragma unroll
            for (int i = 0; i < 4; i++)
                #pragma unroll
                for (int rr = 0; rr < 4; rr++) sums[i][rr] = 0.0f;
            curout = o;
        }

        f32x4 acc[4][4];
        #pragma unroll
        for (int i = 0; i < 4; i++)
            #pragma unroll
            for (int j = 0; j < 4; j++)
                acc[i][j] = (f32x4){0.f, 0.f, 0.f, 0.f};

        #pragma unroll
        for (int k8 = 0; k8 < 8; k8++) {
            int rb = k8 & 3;
            int rs = (k8 + 2) & 3;
            if (!last || k8 < 6) {
                // stage chunk c+2 (possibly first chunks of next tile)
                int c2  = s * 8 + k8 + 2;
                int tl2 = yb + ((c2 >> 3) << 4);
                int kk2 = (c2 & 7) * 32;
                const unsigned short* g =
                    E + (size_t)(tl2 * 128 + 32 * wave + col) * DDIM + kk2 + quad * 8;
                gl_lds16(g,             &Bs[rs][wave * 1024]);
                gl_lds16(g + 16 * DDIM, &Bs[rs][wave * 1024 + 512]);
                wait_vmcnt4();          // chunk c done; c+1,c+2 stay in flight
            } else if (k8 == 6) {
                wait_vmcnt2();
            } else {
                wait_vmcnt0();
            }
            raw_barrier();              // no compiler-inserted vmcnt(0) drain

            bf16x8 bfv[4];
            #pragma unroll
            for (int j = 0; j < 4; j++)
                bfv[j] = *(const bf16x8*)(&Bs[rb][(wn * 4 + j) * 512 + quad * 128 + col * 8]);
            #pragma unroll
            for (int j = 0; j < 4; j++)
                #pragma unroll
                for (int i = 0; i < 4; i++)
                    acc[i][j] = __builtin_amdgcn_mfma_f32_16x16x32_bf16(
                        afr[i][k8], bfv[j], acc[i][j], 0, 0, 0);
        }

        // per-tile epilogue: weighted exp, DPP-reduce over 64 n, accumulate.
        // Runs while chunks of the next tile are in flight.
        #pragma unroll
        for (int i = 0; i < 4; i++)
            #pragma unroll
            for (int rr = 0; rr < 4; rr++) {
                float sv = wj[0] * __expf(acc[i][0][rr]) + wj[1] * __expf(acc[i][1][rr])
                         + wj[2] * __expf(acc[i][2][rr]) + wj[3] * __expf(acc[i][3][rr]);
                sums[i][rr] += red16(sv);
            }
    }

    // final flush
    if (col == 0) {
        #pragma unroll
        for (int i = 0; i < 4; i++)
            #pragma unroll
            for (int rr = 0; rr < 4; rr++)
                atomicAdd(curout + outrow + 16 * i + quad * 4 + rr, sums[i][rr]);
    }
}

// ---------------------------------------------------------------------------
// Kernel 3: fr alignment (per-batch 64x64 exp-sum, weight 1/denom_fr) with
// inline W_fr[x_fr] gather+convert for A and the final loss fused in.
// ---------------------------------------------------------------------------
__global__ __launch_bounds__(256) void expsum_gemm64_loss(
    const float* __restrict__ W_fr,         // [V_FR x 256] fp32
    const int* __restrict__ x_fr,           // [B*64]
    const unsigned short* __restrict__ Bm,  // z_bf  [B][64 x 256]
    const float* __restrict__ denom_fr,     // [B*64]
    const float* __restrict__ denom_en,     // [B*64]
    const float* __restrict__ en_score,     // [B*64]
    const float* __restrict__ en_mask,
    const float* __restrict__ fr_mask,
    float* __restrict__ outloss)            // [128]: en | fr
{
    __shared__ __align__(16) unsigned short lda[TM * LDT];
    __shared__ __align__(16) unsigned short ldb[TN * LDT];
    __shared__ float tbuf[64];

    int batch = blockIdx.x;
    const unsigned short* Bb = Bm + (size_t)batch * TN * DDIM;

    int t      = threadIdx.x;
    int srow   = t >> 2;
    int schunk = t & 3;
    int lane   = t & 63;
    int wave   = t >> 6;
    int col    = lane & 15;
    int quad   = lane >> 4;

    int aidx = x_fr[batch * 64 + srow];
    const float* Arow = W_fr + (size_t)aidx * DDIM;

    f32x4 acc0 = {0.f,0.f,0.f,0.f};
    f32x4 acc1 = {0.f,0.f,0.f,0.f};
    f32x4 acc2 = {0.f,0.f,0.f,0.f};
    f32x4 acc3 = {0.f,0.f,0.f,0.f};

    for (int kk = 0; kk < DDIM; kk += 32) {
        float4 f0 = *(const float4*)(Arow + kk + schunk * 8);
        float4 f1 = *(const float4*)(Arow + kk + schunk * 8 + 4);
        uint4 bv = *(const uint4*)(Bb + (size_t)srow * DDIM + kk + schunk * 8);
        ushort4 ua; ua.x = f2bf(f0.x); ua.y = f2bf(f0.y); ua.z = f2bf(f0.z); ua.w = f2bf(f0.w);
        ushort4 ub; ub.x = f2bf(f1.x); ub.y = f2bf(f1.y); ub.z = f2bf(f1.z); ub.w = f2bf(f1.w);
        __syncthreads();
        *(ushort4*)(lda + srow * LDT + schunk * 8)     = ua;
        *(ushort4*)(lda + srow * LDT + schunk * 8 + 4) = ub;
        *(uint4*)(ldb + srow * LDT + schunk * 8) = bv;
        __syncthreads();

        bf16x8 af = *(const bf16x8*)(lda + (wave * 16 + col) * LDT + quad * 8);
        bf16x8 b0 = *(const bf16x8*)(ldb + ( 0 + col) * LDT + quad * 8);
        bf16x8 b1 = *(const bf16x8*)(ldb + (16 + col) * LDT + quad * 8);
        bf16x8 b2 = *(const bf16x8*)(ldb + (32 + col) * LDT + quad * 8);
        bf16x8 b3 = *(const bf16x8*)(ldb + (48 + col) * LDT + quad * 8);
        acc0 = __builtin_amdgcn_mfma_f32_16x16x32_bf16(af, b0, acc0, 0, 0, 0);
        acc1 = __builtin_amdgcn_mfma_f32_16x16x32_bf16(af, b1, acc1, 0, 0, 0);
        acc2 = __builtin_amdgcn_mfma_f32_16x16x32_bf16(af, b2, acc2, 0, 0, 0);
        acc3 = __builtin_amdgcn_mfma_f32_16x16x32_bf16(af, b3, acc3, 0, 0, 0);
    }

    const float* db = denom_fr + batch * 64;
    float w0 = 1.0f / db[ 0 + col];
    float w1 = 1.0f / db[16 + col];
    float w2 = 1.0f / db[32 + col];
    float w3 = 1.0f / db[48 + col];

    float tot0 = w0 * __expf(acc0.x) + w1 * __expf(acc1.x) + w2 * __expf(acc2.x) + w3 * __expf(acc3.x);
    float tot1 = w0 * __expf(acc0.y) + w1 * __expf(acc1.y) + w2 * __expf(acc2.y) + w3 * __expf(acc3.y);
    float tot2 = w0 * __expf(acc0.z) + w1 * __expf(acc1.z) + w2 * __expf(acc2.z) + w3 * __expf(acc3.z);
    float tot3 = w0 * __expf(acc0.w) + w1 * __expf(acc1.w) + w2 * __expf(acc2.w) + w3 * __expf(acc3.w);

    #pragma unroll
    for (int m = 1; m < 16; m <<= 1) {
        tot0 += __shfl_xor(tot0, m);
        tot1 += __shfl_xor(tot1, m);
        tot2 += __shfl_xor(tot2, m);
        tot3 += __shfl_xor(tot3, m);
    }
    if (col == 0) {
        int base = wave * 16 + quad * 4;
        tbuf[base + 0] = tot0; tbuf[base + 1] = tot1;
        tbuf[base + 2] = tot2; tbuf[base + 3] = tot3;
    }
    __syncthreads();

    if (t < 64) {
        int i = batch * 64 + t;
        float a = (en_score[i] - __logf(denom_en[i])) * en_mask[i];
        float c = __logf(tbuf[t]) * fr_mask[i];
        #pragma unroll
        for (int m = 32; m; m >>= 1) { a += __shfl_xor(a, m); c += __shfl_xor(c, m); }
        if (t == 0) { outloss[batch] = a; outloss[64 + batch] = c; }
    }
}

extern "C" void kernel_launch(void* const* d_in, const int* in_sizes, int n_in,
                              void* d_out, int out_size, void* d_ws, size_t ws_size,
                              hipStream_t stream)
{
    const float* zs       = (const float*)d_in[0];
    const int*   x_en     = (const int*)d_in[1];
    const int*   x_fr     = (const int*)d_in[2];
    const float* en_mask  = (const float*)d_in[3];
    const float* fr_mask  = (const float*)d_in[4];
    const float* W_en     = (const float*)d_in[5];
    const float* W_fr     = (const float*)d_in[6];
    const int*   pos_en   = (const int*)d_in[7];
    const int*   neg_en   = (const int*)d_in[8];
    const int*   pos_fr   = (const int*)d_in[9];
    const int*   neg_fr   = (const int*)d_in[10];
    const float* kappa_en = (const float*)d_in[11];
    const float* kappa_fr = (const float*)d_in[12];

    int Pe  = in_sizes[7];
    int Pf  = in_sizes[9];
    int Lpe = (Pe + NEGN + 127) & ~127;   // 128-aligned n-tiles
    int Lpf = (Pf + NEGN + 127) & ~127;
    int Ltot = Lpe + Lpf;
    int NT   = Ltot / 128;

    char* w = (char*)d_ws;
    float* denom_en = (float*)w; w += NTOK * 4;
    float* denom_fr = (float*)w; w += NTOK * 4;
    float* en_score = (float*)w; w += NTOK * 4;
    float* w_all    = (float*)w; w += (size_t)Ltot * 4;
    unsigned short* z_bf  = (unsigned short*)w; w += (size_t)NTOK * DDIM * 2;
    unsigned short* E_all = (unsigned short*)w; w += (size_t)Ltot * DDIM * 2;

    int totrows = NTOK + Lpe + Lpf + NTOK;
    gather_kernel<<<(totrows + 3) / 4, 256, 0, stream>>>(
        zs, W_en, W_fr, pos_en, neg_en, pos_fr, neg_fr, x_en,
        kappa_en, kappa_fr, z_bf, E_all, E_all + (size_t)Lpe * DDIM,
        w_all, w_all + Lpe, en_score, denom_en, denom_fr, Pe, Pf, Lpe, Lpf);

    // fused denominators: shared staging + raw barrier + fine-grained vmcnt
    expsum_stream<<<dim3(32, 16), 256, 0, stream>>>(
        z_bf, E_all, w_all, denom_en, denom_fr, Lpe, NT);

    // fr alignment + inline W_fr gather + fused loss
    expsum_gemm64_loss<<<64, 256, 0, stream>>>(
        W_fr, x_fr, z_bf, denom_fr, denom_en, en_score, en_mask, fr_mask,
        (float*)d_out);
}